// Round 2
// baseline (457.117 us; speedup 1.0000x reference)
//
#include <hip/hip_runtime.h>

// Problem constants
#define N_    8
#define TP_   2048
#define E_    4096
#define S_    8
#define C_    64
#define T_    16384      // TP_*S_
#define TS_   131072     // T_*S_
#define OUTW  17         // V+1
#define OUT_ELEMS 17825792  // N_*TS_*OUTW
#define F4_PER_N 557056     // 16384 rows * 34 float4 per row
#define F4_TOTAL 4456448    // OUT_ELEMS/4
#define KSTEPS 128          // E_ / 32
#define GEMM_BLOCKS 2048    // 128-thread blocks, one 16-row tile each (loop if more)
#define FILL_BLOCKS 4352    // F4_TOTAL / 1024 (128 thr * 8 float4)
#define MPREP_BLOCKS 256    // one per 16-k half-kstep

typedef __attribute__((ext_vector_type(8))) short short8;
typedef __attribute__((ext_vector_type(4))) float float4v;

static __device__ __forceinline__ unsigned short f2bf(float f) {
    unsigned int u = __builtin_bit_cast(unsigned int, f);
    u += 0x7FFFu + ((u >> 16) & 1u);   // round-to-nearest-even
    return (unsigned short)(u >> 16);
}
static __device__ __forceinline__ float bf2f(unsigned short h) {
    return __builtin_bit_cast(float, (unsigned int)h << 16);
}
// packed f32x2 -> bf16x2 (RNE), gfx950 native; no builtin exists (m240)
static __device__ __forceinline__ unsigned int cvt_pk(float lo, float hi) {
    unsigned int r;
    asm("v_cvt_pk_bf16_f32 %0, %1, %2" : "=v"(r) : "v"(lo), "v"(hi));
    return r;
}

// ---------------------------------------------------------------------------
// prep_compact: blocks 0..63 = compact (proven logic; tile granularity now 16
// rows); blocks 64..319 = M precompute.
//   M[s][e][s2] = sum_c W1[e,c,s]*W2[c,s2]  -> contracts away the C=64 dim.
//   Stored bf16 hi/lo split in MFMA B-fragment order:
//   Mfrag[((s*128 + kstep)*64 + lane)*8 + j] = M[kstep*32+(lane>>4)*8+j][lane&15]
// ---------------------------------------------------------------------------
__global__ __launch_bounds__(256) void prep_compact_kernel(
    const float* __restrict__ W1, const float* __restrict__ b1,
    const float* __restrict__ W2, const float* __restrict__ b2,
    const int* __restrict__ value, const int* __restrict__ depth,
    unsigned short* __restrict__ Mhi, unsigned short* __restrict__ Mlo,
    float* __restrict__ K2,
    int* __restrict__ cnt_ns, int* __restrict__ cnt_total,
    int* __restrict__ tile_counter, int* __restrict__ tiles,
    int* __restrict__ sel_tp, int* __restrict__ sel_j)
{
    const int tid = threadIdx.x;
    const int b   = blockIdx.x;

    if (b < 64) {
        // ---------------- compact ----------------
        __shared__ int idx_sh;
        __shared__ unsigned int wsum[4];
        const int g = b;                   // n*8 + s
        const int n = g >> 3;
        const int s = g & 7;
        const int lane = tid & 63;
        const int wv   = tid >> 6;

        const int* d = depth + (size_t)n * T_;
        if (tid < 64) {                    // wave 0: 64-ary search, 3 rounds
            int maxv = d[T_ - 1];
            int lower = 0, upper = T_ - 1;
            for (int rnd = 0; rnd < 3; ++rnd) {
                int span = upper - lower;
                int step = (span + 63) >> 6;
                if (step < 1) step = 1;
                int p = lower + lane * step;
                if (p > upper) p = upper;
                unsigned long long bb = __ballot(d[p] == maxv);
                int f = __ffsll((long long)bb) - 1;
                int nu = lower + f * step; if (nu > upper) nu = upper;
                int nl = (f == 0) ? lower : lower + (f - 1) * step + 1;
                if (nl > nu) nl = nu;
                lower = nl; upper = nu;
            }
            if (lane == 0) idx_sh = lower;
        }
        __syncthreads();
        const int idx = idx_sh;
        const int4* val4 = (const int4*)(value + (size_t)n * T_);

        const int b4 = tid * 16;
        unsigned int packed = 0;           // (any-count << 16) | s-residue count
        for (int i = 0; i < 16; ++i) {
            int4 v = val4[b4 + i];
            int t = (b4 + i) * 4;
            if (t + 0 < idx && v.x == 2) { packed += 0x10000u; if (((t + 0) & 7) == s) packed += 1u; }
            if (t + 1 < idx && v.y == 2) { packed += 0x10000u; if (((t + 1) & 7) == s) packed += 1u; }
            if (t + 2 < idx && v.z == 2) { packed += 0x10000u; if (((t + 2) & 7) == s) packed += 1u; }
            if (t + 3 < idx && v.w == 2) { packed += 0x10000u; if (((t + 3) & 7) == s) packed += 1u; }
        }
        unsigned int inc = packed;
#pragma unroll
        for (int off = 1; off < 64; off <<= 1) {
            unsigned int u = __shfl_up((int)inc, off, 64);
            if (lane >= off) inc += u;
        }
        if (lane == 63) wsum[wv] = inc;
        __syncthreads();
        unsigned int woff = 0;
        for (int ww = 0; ww < wv; ++ww) woff += wsum[ww];
        unsigned int excl = woff + inc - packed;
        int any_rank = (int)(excl >> 16);
        int s_rank   = (int)(excl & 0xFFFFu);
        for (int i = 0; i < 16; ++i) {
            int4 v = val4[b4 + i];
            int vv[4] = { v.x, v.y, v.z, v.w };
            int t = (b4 + i) * 4;
#pragma unroll
            for (int e = 0; e < 4; ++e) {
                int tt = t + e;
                if (tt < idx && vv[e] == 2) {
                    if ((tt & 7) == s) {
                        sel_tp[g * 2048 + s_rank] = tt >> 3;
                        sel_j [g * 2048 + s_rank] = any_rank;
                        ++s_rank;
                    }
                    ++any_rank;
                }
            }
        }
        if (tid == 255) {
            unsigned int tot = woff + inc;
            int cnt = (int)(tot & 0xFFFFu);
            cnt_ns[g] = cnt;
            if (s == 0) cnt_total[n] = (int)(tot >> 16);
            int ntl = (cnt + 15) >> 4;                 // 16-row tiles
            int base = atomicAdd(tile_counter, ntl);
            for (int i = 0; i < ntl; ++i) tiles[base + i] = (g << 8) | i;
        }
        return;
    }

    // ---------------- M precompute ----------------
    __shared__ float W1t[16 * 512];   // 32 KB: 16 contiguous W1 rows (e-major)
    __shared__ float W2s[512];

    if (b == 64 && tid < 8) {
        int s2 = tid;
        float acc = b2[0];
        for (int c = 0; c < C_; ++c) acc += b1[c] * W2[c * S_ + s2];
        K2[s2] = acc;
    }

    const int kk    = b - 64;          // 0..255
    const int kstep = kk >> 1;         // 0..127
    const int h     = kk & 1;          // which 16-k half of the 32-k step
    const int k0    = kstep * 32 + h * 16;

    for (int i = tid; i < 512; i += 256) W2s[i] = W2[i];
    {
        const float4* src = (const float4*)(W1 + (size_t)k0 * 512);
        float4* dst = (float4*)W1t;
        for (int i = tid; i < 16 * 128; i += 256) dst[i] = src[i];
    }
    __syncthreads();

    const int s    = tid >> 5;         // 0..7
    const int lsub = tid & 31;
    const int lane = h * 32 + lsub;    // fragment lane 0..63
    const int qq   = lsub >> 4;        // local row-group within the 16 k's
    const int s2   = lane & 15;        // output col (valid if < 8)

    float accj[8] = {0.f,0.f,0.f,0.f,0.f,0.f,0.f,0.f};
    if (s2 < 8) {
        for (int c = 0; c < C_; ++c) {
            float w2 = W2s[c * 8 + s2];
            int base = c * 8 + s;
#pragma unroll
            for (int j = 0; j < 8; ++j)
                accj[j] += W1t[(qq * 8 + j) * 512 + base] * w2;
        }
    }
    size_t o = ((size_t)(s * KSTEPS + kstep) * 64 + lane) * 8;
#pragma unroll
    for (int j = 0; j < 8; ++j) {
        unsigned short hi = f2bf(accj[j]);
        unsigned short lo = f2bf(accj[j] - bf2f(hi));
        Mhi[o + j] = hi;
        Mlo[o + j] = lo;
    }
}

// ---------------------------------------------------------------------------
// main (128-thread blocks): blocks < GEMM_BLOCKS run the gathered GEMM with
// 16-row tiles and K split x2 across the block's 2 waves (wave w: ksteps
// [w*64, w*64+64)).  2x resident waves/CU vs round 1 and half the per-wave
// serial chain -> covers the L2/LLC gather latency.  Inner loop uses native
// v_cvt_pk_bf16_f32 (4 instrs) instead of integer-emulated f2bf (~32 instrs).
// Partials combine via 2 KB LDS; epilogue = fused conv2-bias + W3 outer prod.
// Blocks >= GEMM_BLOCKS do the fill (disjoint rows j >= cnt_total) and
// backfill CU slots while GEMM blocks stall on gather latency.
// ---------------------------------------------------------------------------
__global__ __launch_bounds__(128) void main_kernel(
    const float* __restrict__ x,
    const unsigned short* __restrict__ Mhi, const unsigned short* __restrict__ Mlo,
    const int* __restrict__ tile_counter, const int* __restrict__ tiles,
    const int* __restrict__ cnt_ns, const int* __restrict__ sel_tp,
    const int* __restrict__ sel_j, const float* __restrict__ K2,
    const float* __restrict__ W3, const float* __restrict__ b2,
    const int* __restrict__ cnt_total, float* __restrict__ out)
{
    const int tid = threadIdx.x;

    if (blockIdx.x >= GEMM_BLOCKS) {
        // ---------------- fill ----------------
        __shared__ float pat[136];
        for (int i = tid; i < 136; i += 128) pat[i] = b2[0] * W3[i % OUTW];
        __syncthreads();
        const int fb = blockIdx.x - GEMM_BLOCKS;
#pragma unroll
        for (int it = 0; it < 8; ++it) {
            int i4 = fb * 1024 + it * 128 + tid;   // < F4_TOTAL exactly
            int n   = i4 / F4_PER_N;
            int rem = i4 - n * F4_PER_N;
            int j   = rem / 34;
            if (j >= cnt_total[n]) {
                int o = (rem - j * 34) * 4;
                float4 v = { pat[o], pat[o + 1], pat[o + 2], pat[o + 3] };
                *(float4*)&out[(size_t)i4 * 4] = v;
            }
        }
        return;
    }

    // ---------------- GEMM ----------------
    __shared__ int tp_l[16], j_l[16];
    __shared__ float pacc[2][64][4];
    __shared__ float y2s[16][8];
    __shared__ float W3s[OUTW];
    __shared__ float K2s[S_];

    if (tid < OUTW) W3s[tid] = W3[tid];
    if (tid < S_)   K2s[tid] = K2[tid];

    const int ntile = *tile_counter;
    const int lane = tid & 63;
    const int w    = tid >> 6;        // wave id = K half
    const int m    = lane & 15;       // x-row within tile (A row)
    const int q    = lane >> 4;       // k sub-slice within 32-k step

    for (int ti = blockIdx.x; ti < ntile; ti += GEMM_BLOCKS) {
        const int ent = tiles[ti];
        const int g = ent >> 8;
        const int n = g >> 3;
        const int s = g & 7;
        const int m0 = (ent & 255) * 16;
        const int rows = min(16, cnt_ns[g] - m0);

        __syncthreads();   // previous tile's epilogue reads fully done
        if (tid < 16) {
            int tp = 0, j = 0;
            if (tid < rows) {
                tp = sel_tp[g * 2048 + m0 + tid];
                j  = sel_j [g * 2048 + m0 + tid];
            }
            tp_l[tid] = tp;
            j_l[tid]  = j;
        }
        __syncthreads();

        const float* arow = x + ((size_t)n * TP_ + tp_l[m]) * E_ + w * 2048 + q * 8;
        const unsigned short* bh = Mhi + ((size_t)(s * KSTEPS + w * 64) * 64 + lane) * 8;
        const unsigned short* bl = Mlo + ((size_t)(s * KSTEPS + w * 64) * 64 + lane) * 8;

        float4v acc = {0.f, 0.f, 0.f, 0.f};

        // 2-step register prefetch, named sets (compile-time parity)
        float4 A00 = *(const float4*)(arow);
        float4 A01 = *(const float4*)(arow + 4);
        short8 Bh0 = *(const short8*)(bh);
        short8 Bl0 = *(const short8*)(bl);
        float4 A10 = *(const float4*)(arow + 32);
        float4 A11 = *(const float4*)(arow + 36);
        short8 Bh1 = *(const short8*)(bh + 512);
        short8 Bl1 = *(const short8*)(bl + 512);

#define STEP(P, A0, A1, BH, BL)                                                \
        {                                                                      \
            int4 aw;                                                           \
            aw.x = (int)cvt_pk(A0.x, A0.y);                                    \
            aw.y = (int)cvt_pk(A0.z, A0.w);                                    \
            aw.z = (int)cvt_pk(A1.x, A1.y);                                    \
            aw.w = (int)cvt_pk(A1.z, A1.w);                                    \
            short8 av = __builtin_bit_cast(short8, aw);                        \
            short8 bhc = BH, blc = BL;                                         \
            if (ks + 2 + P < 64) {                                             \
                const float* ap = arow + (size_t)(ks + 2 + P) * 32;            \
                A0 = *(const float4*)(ap);                                     \
                A1 = *(const float4*)(ap + 4);                                 \
                BH = *(const short8*)(bh + (size_t)(ks + 2 + P) * 512);        \
                BL = *(const short8*)(bl + (size_t)(ks + 2 + P) * 512);        \
            }                                                                  \
            acc = __builtin_amdgcn_mfma_f32_16x16x32_bf16(av, bhc, acc, 0, 0, 0); \
            acc = __builtin_amdgcn_mfma_f32_16x16x32_bf16(av, blc, acc, 0, 0, 0); \
        }

        for (int ks = 0; ks < 64; ks += 2) {
            STEP(0, A00, A01, Bh0, Bl0)
            STEP(1, A10, A11, Bh1, Bl1)
        }
#undef STEP

        // combine K halves: D row = q*4+rr, col = lane&15 (s2, valid < 8)
        *(float4v*)&pacc[w][lane][0] = acc;
        __syncthreads();
        {
            int row = tid >> 3;            // 0..15
            int s2  = tid & 7;
            int ln  = ((row >> 2) << 4) | s2;
            int rr  = row & 3;
            y2s[row][s2] = K2s[s2] + pacc[0][ln][rr] + pacc[1][ln][rr];
        }
        __syncthreads();

        // coalesced writes: each output row is 136 consecutive floats = 34 f4
        for (int task = tid; task < 16 * 34; task += 128) {
            int row = task / 34;
            int f   = task - row * 34;
            if (row < rows) {
                float4 v;
                float* vp = (float*)&v;
#pragma unroll
                for (int e = 0; e < 4; ++e) {
                    int idx = f * 4 + e;
                    int s2  = (idx * 241) >> 12;   // idx/17 for idx<136
                    int vi  = idx - s2 * OUTW;
                    vp[e] = y2s[row][s2] * W3s[vi];
                }
                *(float4*)&out[((size_t)n * TS_ + (size_t)j_l[row] * S_) * OUTW + f * 4] = v;
            }
        }
    }
}

// ---------------------------------------------------------------------------
extern "C" void kernel_launch(void* const* d_in, const int* in_sizes, int n_in,
                              void* d_out, int out_size, void* d_ws, size_t ws_size,
                              hipStream_t stream) {
    const float* x     = (const float*)d_in[0];
    const int*   value = (const int*)d_in[1];
    const int*   depth = (const int*)d_in[2];
    // d_in[3] = pos (unused by reference)
    const float* W1    = (const float*)d_in[4];
    const float* b1    = (const float*)d_in[5];
    const float* W2    = (const float*)d_in[6];
    const float* b2    = (const float*)d_in[7];
    const float* W3    = (const float*)d_in[8];
    float* out = (float*)d_out;

    // workspace layout (~3.3 MB)
    unsigned short* Mhi = (unsigned short*)d_ws;            // 8*128*64*8 = 1 MB
    unsigned short* Mlo = Mhi + 8 * KSTEPS * 64 * 8;        // 1 MB
    float* K2          = (float*)(Mlo + 8 * KSTEPS * 64 * 8);  // 8
    int* tile_counter  = (int*)(K2 + 8);                    // 1
    int* cnt_ns        = tile_counter + 1;                  // 64
    int* cnt_total     = cnt_ns + 64;                       // 8
    int* tiles         = cnt_total + 8;                     // 8192 max (16-row)
    int* sel_tp        = tiles + 8192;                      // 64*2048
    int* sel_j         = sel_tp + 64 * 2048;                // 64*2048

    hipMemsetAsync(tile_counter, 0, sizeof(int), stream);

    prep_compact_kernel<<<64 + MPREP_BLOCKS, 256, 0, stream>>>(
        W1, b1, W2, b2, value, depth, Mhi, Mlo, K2,
        cnt_ns, cnt_total, tile_counter, tiles, sel_tp, sel_j);

    main_kernel<<<GEMM_BLOCKS + FILL_BLOCKS, 128, 0, stream>>>(
        x, Mhi, Mlo, tile_counter, tiles, cnt_ns, sel_tp, sel_j,
        K2, W3, b2, cnt_total, out);
}

// Round 3
// 452.264 us; speedup vs baseline: 1.0107x; 1.0107x over previous
//
#include <hip/hip_runtime.h>

// Problem constants
#define N_    8
#define TP_   2048
#define E_    4096
#define S_    8
#define C_    64
#define T_    16384      // TP_*S_
#define TS_   131072     // T_*S_
#define OUTW  17         // V+1
#define OUT_ELEMS 17825792  // N_*TS_*OUTW
#define F4_PER_N 557056     // 16384 rows * 34 float4 per row
#define F4_TOTAL 4456448    // OUT_ELEMS/4
#define KSTEPS 128          // E_ / 32
#define GEMM_BLOCKS 512     // >= max tiles (8 n * 64 tiles)
#define FILL_BLOCKS 4352    // F4_TOTAL / 1024 (256 thr * 4 float4)

typedef __attribute__((ext_vector_type(8))) short short8;
typedef __attribute__((ext_vector_type(4))) float float4v;

static __device__ __forceinline__ unsigned short f2bf(float f) {
    unsigned int u = __builtin_bit_cast(unsigned int, f);
    u += 0x7FFFu + ((u >> 16) & 1u);   // round-to-nearest-even
    return (unsigned short)(u >> 16);
}
static __device__ __forceinline__ float bf2f(unsigned short h) {
    return __builtin_bit_cast(float, (unsigned int)h << 16);
}
// packed f32x2 -> bf16x2 (RNE), gfx950 native; no builtin exists (m240)
static __device__ __forceinline__ unsigned int cvt_pk(float lo, float hi) {
    unsigned int r;
    asm("v_cvt_pk_bf16_f32 %0, %1, %2" : "=v"(r) : "v"(lo), "v"(hi));
    return r;
}

// ---------------------------------------------------------------------------
// prep_compact:
//   blocks 0..7   = per-n compact with tp-DEDUP: emits unique-tp row list
//                   (urow_tp) and per-s output-rank table (uslot, -1 = absent).
//                   j-rank = rank among selected t in ascending t order ==
//                   reference's stable compaction order.
//   blocks 8..135 = M_all precompute, block = kstep (32 k's):
//                   M_all[k][scol] = sum_c W1[k,c,scol>>3]*W2[c,scol&7]
//                   stored bf16 hi/lo in MFMA B-fragment order:
//                   frag[((ct*128+kstep)*64+lane)*8+j] = M_all[kstep*32+(lane>>4)*8+j][ct*16+(lane&15)]
//                   All 16 fragment cols valid (no zero padding).
// ---------------------------------------------------------------------------
__global__ __launch_bounds__(256) void prep_compact_kernel(
    const float* __restrict__ W1, const float* __restrict__ b1,
    const float* __restrict__ W2, const float* __restrict__ b2,
    const int* __restrict__ value, const int* __restrict__ depth,
    unsigned short* __restrict__ Mhi, unsigned short* __restrict__ Mlo,
    float* __restrict__ K2,
    int* __restrict__ ucnt, int* __restrict__ cnt_total,
    int* __restrict__ tile_counter, int* __restrict__ tiles,
    int* __restrict__ urow_tp, int* __restrict__ uslot)
{
    const int tid = threadIdx.x;
    const int b   = blockIdx.x;

    if (b < 8) {
        // ---------------- compact (per n, dedup) ----------------
        __shared__ int idx_sh;
        __shared__ unsigned int wsum[4];
        const int n = b;
        const int lane = tid & 63;
        const int wv   = tid >> 6;

        const int* d = depth + (size_t)n * T_;
        if (tid < 64) {                    // wave 0: 64-ary search, 3 rounds
            int maxv = d[T_ - 1];
            int lower = 0, upper = T_ - 1;
            for (int rnd = 0; rnd < 3; ++rnd) {
                int span = upper - lower;
                int step = (span + 63) >> 6;
                if (step < 1) step = 1;
                int p = lower + lane * step;
                if (p > upper) p = upper;
                unsigned long long bb = __ballot(d[p] == maxv);
                int f = __ffsll((long long)bb) - 1;   // never 0: d[upper]==maxv
                int nu = lower + f * step; if (nu > upper) nu = upper;
                int nl = (f == 0) ? lower : lower + (f - 1) * step + 1;
                if (nl > nu) nl = nu;
                lower = nl; upper = nu;
            }
            if (lane == 0) idx_sh = lower;
        }
        __syncthreads();
        const int idx = idx_sh;
        const int4* val4 = (const int4*)(value + (size_t)n * T_);

        // thread owns t in [tid*64, tid*64+64) = 8 whole tp's
        const int b4 = tid * 16;
        unsigned long long mask = 0ull;    // bit lt set if t = tid*64+lt selected
        for (int i = 0; i < 16; ++i) {
            int4 v = val4[b4 + i];
            int t = (b4 + i) * 4;
            int lt = t - tid * 64;
            if (t + 0 < idx && v.x == 2) mask |= 1ull << (lt + 0);
            if (t + 1 < idx && v.y == 2) mask |= 1ull << (lt + 1);
            if (t + 2 < idx && v.z == 2) mask |= 1ull << (lt + 2);
            if (t + 3 < idx && v.w == 2) mask |= 1ull << (lt + 3);
        }
        int selc = __popcll(mask);
        int uc = 0;
#pragma unroll
        for (int p = 0; p < 8; ++p) if ((mask >> (8 * p)) & 255ull) ++uc;

        unsigned int packed = ((unsigned int)selc << 16) | (unsigned int)uc;
        unsigned int inc = packed;
#pragma unroll
        for (int off = 1; off < 64; off <<= 1) {
            unsigned int u = __shfl_up((int)inc, off, 64);
            if (lane >= off) inc += u;
        }
        if (lane == 63) wsum[wv] = inc;
        __syncthreads();
        unsigned int woff = 0;
        for (int ww = 0; ww < wv; ++ww) woff += wsum[ww];
        unsigned int excl = woff + inc - packed;
        int j = (int)(excl >> 16);
        int u = (int)(excl & 0xFFFFu);
#pragma unroll
        for (int p = 0; p < 8; ++p) {
            unsigned int bmask = (unsigned int)((mask >> (8 * p)) & 255ull);
            if (bmask) {
                urow_tp[n * 2048 + u] = tid * 8 + p;
                int* slot = &uslot[(n * 2048 + u) * 8];
#pragma unroll
                for (int s = 0; s < 8; ++s)
                    slot[s] = ((bmask >> s) & 1u) ? j++ : -1;
                ++u;
            }
        }
        if (tid == 255) {
            unsigned int tot = woff + inc;
            cnt_total[n] = (int)(tot >> 16);
            int un = (int)(tot & 0xFFFFu);
            ucnt[n] = un;
            int ntl = (un + 31) >> 5;                 // 32-row tiles
            int base = atomicAdd(tile_counter, ntl);
            for (int i = 0; i < ntl; ++i) tiles[base + i] = (n << 8) | i;
        }
        return;
    }

    // ---------------- M_all precompute ----------------
    __shared__ float W1t[32 * 512];   // 64 KB: 32 contiguous W1 rows (e-major)
    __shared__ float W2s[512];

    if (b == 8 && tid < 8) {
        int s2 = tid;
        float acc = b2[0];
        for (int c = 0; c < C_; ++c) acc += b1[c] * W2[c * S_ + s2];
        K2[s2] = acc;
    }

    const int kstep = b - 8;           // 0..127

    for (int i = tid; i < 512; i += 256) W2s[i] = W2[i];
    {
        const float4* src = (const float4*)(W1 + (size_t)kstep * 32 * 512);
        float4* dst = (float4*)W1t;
        for (int i = tid; i < 32 * 128; i += 256) dst[i] = src[i];
    }
    __syncthreads();

    const int ct   = tid >> 6;         // 0..3 (wave = col-tile)
    const int l    = tid & 63;         // fragment lane
    const int q    = l >> 4;
    const int c15  = l & 15;
    const int scol = ct * 16 + c15;    // global output col 0..63
    const int s    = scol >> 3;
    const int s2   = scol & 7;

    float accj[8] = {0.f,0.f,0.f,0.f,0.f,0.f,0.f,0.f};
    for (int c = 0; c < C_; ++c) {
        float w2 = W2s[c * 8 + s2];
        int base = c * 8 + s;
#pragma unroll
        for (int j = 0; j < 8; ++j)
            accj[j] += W1t[(q * 8 + j) * 512 + base] * w2;
    }
    size_t o = ((size_t)(ct * KSTEPS + kstep) * 64 + l) * 8;
#pragma unroll
    for (int j = 0; j < 8; ++j) {
        unsigned short hi = f2bf(accj[j]);
        unsigned short lo = f2bf(accj[j] - bf2f(hi));
        Mhi[o + j] = hi;
        Mlo[o + j] = lo;
    }
}

// ---------------------------------------------------------------------------
// main (256-thread blocks):
//   blocks < GEMM_BLOCKS: dedup'd gathered GEMM. Tile = 32 UNIQUE x-rows x 64
//   output cols (all 8 s x 8 s2 at once -> each unique row read from HBM
//   exactly once). 4 waves = (2 row-halves x 2 col-halves); each wave runs
//   full K=4096 barrier-free with 6 loads + 4 cvt_pk + 4 MFMA per 32-k step,
//   2-phase register prefetch (12 loads in flight). Epilogue scatters the
//   selected (row,s) sub-outputs via an LDS-compacted work list.
//   blocks >= GEMM_BLOCKS: fill rows j >= cnt_total[n] (disjoint).
// ---------------------------------------------------------------------------
__global__ __launch_bounds__(256) void main_kernel(
    const float* __restrict__ x,
    const unsigned short* __restrict__ Mhi, const unsigned short* __restrict__ Mlo,
    const int* __restrict__ tile_counter, const int* __restrict__ tiles,
    const int* __restrict__ ucnt, const int* __restrict__ urow_tp,
    const int* __restrict__ uslot, const float* __restrict__ K2,
    const float* __restrict__ W3, const float* __restrict__ b2,
    const int* __restrict__ cnt_total, float* __restrict__ out)
{
    const int tid = threadIdx.x;

    if (blockIdx.x >= GEMM_BLOCKS) {
        // ---------------- fill ----------------
        __shared__ float pat[136];
        if (tid < 136) pat[tid] = b2[0] * W3[tid % OUTW];
        __syncthreads();
        const int fb = blockIdx.x - GEMM_BLOCKS;
#pragma unroll
        for (int it = 0; it < 4; ++it) {
            int i4 = fb * 1024 + it * 256 + tid;   // < F4_TOTAL exactly
            int n   = i4 / F4_PER_N;
            int rem = i4 - n * F4_PER_N;
            int j   = rem / 34;
            if (j >= cnt_total[n]) {
                int o = (rem - j * 34) * 4;
                float4 v = { pat[o], pat[o + 1], pat[o + 2], pat[o + 3] };
                *(float4*)&out[(size_t)i4 * 4] = v;
            }
        }
        return;
    }

    // ---------------- GEMM ----------------
    __shared__ int tp_l[32];
    __shared__ int js[32][8];
    __shared__ float y64[32][68];      // +4 pad
    __shared__ int olist[256];
    __shared__ int ocnt;
    __shared__ float W3s[OUTW];
    __shared__ float K2s[S_];

    if (tid < OUTW) W3s[tid] = W3[tid];
    if (tid < S_)   K2s[tid] = K2[tid];

    const int ntile = *tile_counter;
    const int lane = tid & 63;
    const int wid  = tid >> 6;
    const int wr   = wid >> 1;        // row-half 0..1
    const int wc   = wid & 1;         // col-half 0..1
    const int m    = lane & 15;
    const int q    = lane >> 4;

    for (int ti = blockIdx.x; ti < ntile; ti += GEMM_BLOCKS) {
        const int ent = tiles[ti];
        const int n  = ent >> 8;
        const int m0 = (ent & 255) * 32;
        const int rows = min(32, ucnt[n] - m0);

        __syncthreads();   // previous tile's epilogue fully done (LDS reuse)
        if (tid < 32)
            tp_l[tid] = (tid < rows) ? urow_tp[n * 2048 + m0 + tid] : 0;
        {
            int r = tid >> 3, s = tid & 7;
            js[r][s] = (r < rows) ? uslot[(n * 2048 + m0 + r) * 8 + s] : -1;
        }
        if (tid == 0) ocnt = 0;
        __syncthreads();

        const float* arow = x + ((size_t)n * TP_ + tp_l[wr * 16 + m]) * E_ + q * 8;
        const int ct0 = wc * 2, ct1 = wc * 2 + 1;
        const unsigned short* bh0 = Mhi + ((size_t)ct0 * KSTEPS * 64 + lane) * 8;
        const unsigned short* bl0 = Mlo + ((size_t)ct0 * KSTEPS * 64 + lane) * 8;
        const unsigned short* bh1 = Mhi + ((size_t)ct1 * KSTEPS * 64 + lane) * 8;
        const unsigned short* bl1 = Mlo + ((size_t)ct1 * KSTEPS * 64 + lane) * 8;

        float4v acc0 = {0.f, 0.f, 0.f, 0.f};
        float4v acc1 = {0.f, 0.f, 0.f, 0.f};

        // 2-phase register prefetch, named sets (compile-time parity)
        float4 A0a = *(const float4*)(arow);
        float4 A1a = *(const float4*)(arow + 4);
        short8 H0a = *(const short8*)(bh0);
        short8 L0a = *(const short8*)(bl0);
        short8 H1a = *(const short8*)(bh1);
        short8 L1a = *(const short8*)(bl1);
        float4 A0b = *(const float4*)(arow + 32);
        float4 A1b = *(const float4*)(arow + 36);
        short8 H0b = *(const short8*)(bh0 + 512);
        short8 L0b = *(const short8*)(bl0 + 512);
        short8 H1b = *(const short8*)(bh1 + 512);
        short8 L1b = *(const short8*)(bl1 + 512);

#define STEP(P, A0, A1, H0, L0, H1, L1)                                        \
        {                                                                      \
            int4 aw;                                                           \
            aw.x = (int)cvt_pk(A0.x, A0.y);                                    \
            aw.y = (int)cvt_pk(A0.z, A0.w);                                    \
            aw.z = (int)cvt_pk(A1.x, A1.y);                                    \
            aw.w = (int)cvt_pk(A1.z, A1.w);                                    \
            short8 av = __builtin_bit_cast(short8, aw);                        \
            short8 h0 = H0, l0 = L0, h1 = H1, l1 = L1;                         \
            if (ks + 2 + P < KSTEPS) {                                         \
                const float* ap = arow + (size_t)(ks + 2 + P) * 32;            \
                size_t bo = (size_t)(ks + 2 + P) * 512;                        \
                A0 = *(const float4*)(ap);                                     \
                A1 = *(const float4*)(ap + 4);                                 \
                H0 = *(const short8*)(bh0 + bo);                               \
                L0 = *(const short8*)(bl0 + bo);                               \
                H1 = *(const short8*)(bh1 + bo);                               \
                L1 = *(const short8*)(bl1 + bo);                               \
            }                                                                  \
            acc0 = __builtin_amdgcn_mfma_f32_16x16x32_bf16(av, h0, acc0, 0, 0, 0); \
            acc0 = __builtin_amdgcn_mfma_f32_16x16x32_bf16(av, l0, acc0, 0, 0, 0); \
            acc1 = __builtin_amdgcn_mfma_f32_16x16x32_bf16(av, h1, acc1, 0, 0, 0); \
            acc1 = __builtin_amdgcn_mfma_f32_16x16x32_bf16(av, l1, acc1, 0, 0, 0); \
        }

        for (int ks = 0; ks < KSTEPS; ks += 2) {
            STEP(0, A0a, A1a, H0a, L0a, H1a, L1a)
            STEP(1, A0b, A1b, H0b, L0b, H1b, L1b)
        }
#undef STEP

        // D layout (m89-verified): col = lane&15, row = (lane>>4)*4 + reg
#pragma unroll
        for (int rr = 0; rr < 4; ++rr) {
            y64[wr * 16 + q * 4 + rr][ct0 * 16 + m] = acc0[rr];
            y64[wr * 16 + q * 4 + rr][ct1 * 16 + m] = acc1[rr];
        }
        __syncthreads();

        // compact the present (row,s) sub-outputs into a work list
        {
            int r = tid >> 3, s = tid & 7;
            int j = js[r][s];
            if (r < rows && j >= 0) {
                int k = atomicAdd(&ocnt, 1);
                olist[k] = (j << 8) | (r << 3) | s;   // j<=16383 fits
            }
        }
        __syncthreads();

        const int oc = ocnt;
        for (int task = tid; task < oc * 34; task += 256) {
            int e34 = task / 34;
            int f   = task - e34 * 34;
            int pk  = olist[e34];
            int j   = pk >> 8;
            int r   = (pk >> 3) & 31;
            int s   = pk & 7;
            float4 v;
            float* vp = (float*)&v;
#pragma unroll
            for (int e = 0; e < 4; ++e) {
                int idx = f * 4 + e;
                int s2  = (idx * 241) >> 12;   // idx/17 for idx<136
                int vi  = idx - s2 * OUTW;
                vp[e] = (y64[r][s * 8 + s2] + K2s[s2]) * W3s[vi];
            }
            *(float4*)&out[((size_t)n * TS_ + (size_t)j * S_) * OUTW + f * 4] = v;
        }
    }
}

// ---------------------------------------------------------------------------
extern "C" void kernel_launch(void* const* d_in, const int* in_sizes, int n_in,
                              void* d_out, int out_size, void* d_ws, size_t ws_size,
                              hipStream_t stream) {
    const float* x     = (const float*)d_in[0];
    const int*   value = (const int*)d_in[1];
    const int*   depth = (const int*)d_in[2];
    // d_in[3] = pos (unused by reference)
    const float* W1    = (const float*)d_in[4];
    const float* b1    = (const float*)d_in[5];
    const float* W2    = (const float*)d_in[6];
    const float* b2    = (const float*)d_in[7];
    const float* W3    = (const float*)d_in[8];
    float* out = (float*)d_out;

    // workspace layout (~1.7 MB)
    unsigned short* Mhi = (unsigned short*)d_ws;            // 4*128*64*8 = 512 KB
    unsigned short* Mlo = Mhi + 4 * KSTEPS * 64 * 8;        // 512 KB
    float* K2          = (float*)(Mlo + 4 * KSTEPS * 64 * 8);  // 8
    int* tile_counter  = (int*)(K2 + 8);                    // 1
    int* ucnt          = tile_counter + 1;                  // 8
    int* cnt_total     = ucnt + 8;                          // 8
    int* tiles         = cnt_total + 8;                     // <=512
    int* urow_tp       = tiles + 512;                       // 8*2048
    int* uslot         = urow_tp + 8 * 2048;                // 8*2048*8

    hipMemsetAsync(tile_counter, 0, sizeof(int), stream);

    prep_compact_kernel<<<8 + KSTEPS, 256, 0, stream>>>(
        W1, b1, W2, b2, value, depth, Mhi, Mlo, K2,
        ucnt, cnt_total, tile_counter, tiles, urow_tp, uslot);

    main_kernel<<<GEMM_BLOCKS + FILL_BLOCKS, 256, 0, stream>>>(
        x, Mhi, Mlo, tile_counter, tiles, ucnt, urow_tp, uslot,
        K2, W3, b2, cnt_total, out);
}